// Round 3
// baseline (1265.735 us; speedup 1.0000x reference)
//
#include <hip/hip_runtime.h>
#include <hip/hip_bf16.h>

#define NN 100000
#define NE 1600000
#define FIN 32
#define FH 16
#define NG 256
#define EPS 1e-5f

// ---------------------------------------------------------------------------
// proj1: per node, y1 = x @ W1l.T, r1 = x @ W1r.T  (both [N,16]).
// Moving the lin_l projection BEFORE aggregation halves the atomic count and
// gather bytes of the agg pass (segment_sum commutes with the linear map).
// ---------------------------------------------------------------------------
__global__ __launch_bounds__(256) void proj1_kernel(
    const float* __restrict__ x,
    const float* __restrict__ W1l, const float* __restrict__ W1r,
    float* __restrict__ y1, float* __restrict__ r1) {
  __shared__ float sWl[FH * FIN];
  __shared__ float sWr[FH * FIN];
  int t = threadIdx.x;
  for (int i = t; i < FH * FIN; i += 256) {
    sWl[i] = W1l[i];
    sWr[i] = W1r[i];
  }
  __syncthreads();

  int n = blockIdx.x * 256 + t;
  if (n >= NN) return;
  float xl[FIN];
#pragma unroll
  for (int k = 0; k < FIN; k += 4) {
    float4 v = *(const float4*)(x + n * FIN + k);
    xl[k] = v.x; xl[k + 1] = v.y; xl[k + 2] = v.z; xl[k + 3] = v.w;
  }
  float yo[FH], ro[FH];
#pragma unroll
  for (int j = 0; j < FH; j++) {
    float a = 0.f, b = 0.f;
#pragma unroll
    for (int k = 0; k < FIN; k++) {
      a += sWl[j * FIN + k] * xl[k];
      b += sWr[j * FIN + k] * xl[k];
    }
    yo[j] = a; ro[j] = b;
  }
#pragma unroll
  for (int j = 0; j < FH; j += 4) {
    *(float4*)(y1 + n * FH + j) = make_float4(yo[j], yo[j + 1], yo[j + 2], yo[j + 3]);
    *(float4*)(r1 + n * FH + j) = make_float4(ro[j], ro[j + 1], ro[j + 2], ro[j + 3]);
  }
}

// ---------------------------------------------------------------------------
// agg: edge-parallel segment-sum of a [N,16] feature table.
// 4 threads/edge, each gathers one float4 and scatters 4 atomics.
// ---------------------------------------------------------------------------
template <bool WITH_DEG>
__global__ __launch_bounds__(256) void agg_kernel(
    const float* __restrict__ feat, const int* __restrict__ ei,
    float* __restrict__ agg, float* __restrict__ deg) {
  int gid = blockIdx.x * 256 + threadIdx.x;
  int e = gid >> 2;
  int c = gid & 3;
  if (e >= NE) return;
  int src = ei[e];
  int dst = ei[NE + e];
  const float4 v = *(const float4*)(feat + src * FH + c * 4);
  float* a = agg + dst * FH + c * 4;
  atomicAdd(a + 0, v.x);
  atomicAdd(a + 1, v.y);
  atomicAdd(a + 2, v.z);
  atomicAdd(a + 3, v.w);
  if (WITH_DEG && c == 0) atomicAdd(deg + dst, 1.0f);
}

// ---------------------------------------------------------------------------
// conv1: elementwise now — h1 = relu(aggP/deg + r1 + b1); BN stats via
// wave shuffle-reduce, one atomic pair per wave per channel.
// ---------------------------------------------------------------------------
__global__ __launch_bounds__(256) void conv1_kernel(
    const float* __restrict__ aggP, const float* __restrict__ r1,
    const float* __restrict__ deg, const float* __restrict__ b1,
    float* __restrict__ h1, float* __restrict__ stats) {
  __shared__ float sb[FH];
  int t = threadIdx.x;
  if (t < FH) sb[t] = b1[t];
  __syncthreads();

  int n = blockIdx.x * 256 + t;
  float h[FH];
  if (n < NN) {
    float invd = 1.0f / fmaxf(deg[n], 1.0f);
#pragma unroll
    for (int k = 0; k < FH; k += 4) {
      float4 av = *(const float4*)(aggP + n * FH + k);
      float4 rv = *(const float4*)(r1 + n * FH + k);
      h[k]     = fmaxf(av.x * invd + rv.x + sb[k], 0.f);
      h[k + 1] = fmaxf(av.y * invd + rv.y + sb[k + 1], 0.f);
      h[k + 2] = fmaxf(av.z * invd + rv.z + sb[k + 2], 0.f);
      h[k + 3] = fmaxf(av.w * invd + rv.w + sb[k + 3], 0.f);
    }
#pragma unroll
    for (int j = 0; j < FH; j += 4)
      *(float4*)(h1 + n * FH + j) = make_float4(h[j], h[j + 1], h[j + 2], h[j + 3]);
  } else {
#pragma unroll
    for (int j = 0; j < FH; j++) h[j] = 0.0f;
  }

#pragma unroll
  for (int j = 0; j < FH; j++) {
    float s = h[j];
    float q = h[j] * h[j];
    for (int off = 32; off; off >>= 1) {
      s += __shfl_xor(s, off);
      q += __shfl_xor(q, off);
    }
    if ((t & 63) == 0) {
      atomicAdd(stats + j, s);
      atomicAdd(stats + FH + j, q);
    }
  }
}

// ---------------------------------------------------------------------------
// bn1_params: finalize BN1 scale/shift from accumulated stats.
// ---------------------------------------------------------------------------
__global__ void bn1_params_kernel(const float* __restrict__ stats,
                                  const float* __restrict__ g1,
                                  const float* __restrict__ be1,
                                  float* __restrict__ scsh) {
  int c = threadIdx.x;
  if (c >= FH) return;
  float m = stats[c] * (1.0f / NN);
  float v = stats[FH + c] * (1.0f / NN) - m * m;
  float sc = g1[c] * rsqrtf(v + EPS);
  scsh[c] = sc;
  scsh[FH + c] = be1[c] - m * sc;
}

// ---------------------------------------------------------------------------
// proj2: per node, hb = bn1(h1) applied on the fly (fuses the BN-apply pass),
// then p2 = hb @ W2l.T, r2 = hb @ W2r.T.
// ---------------------------------------------------------------------------
__global__ __launch_bounds__(256) void proj2_kernel(
    const float* __restrict__ h1, const float* __restrict__ scsh,
    const float* __restrict__ W2l, const float* __restrict__ W2r,
    float* __restrict__ p2, float* __restrict__ r2) {
  __shared__ float sWl[FH * FH];
  __shared__ float sWr[FH * FH];
  __shared__ float sc[FH], sh[FH];
  int t = threadIdx.x;
  if (t < FH * FH) {
    sWl[t] = W2l[t];
    sWr[t] = W2r[t];
  }
  if (t < FH) {
    sc[t] = scsh[t];
    sh[t] = scsh[FH + t];
  }
  __syncthreads();

  int n = blockIdx.x * 256 + t;
  if (n >= NN) return;
  float hb[FH];
#pragma unroll
  for (int k = 0; k < FH; k += 4) {
    float4 v = *(const float4*)(h1 + n * FH + k);
    hb[k]     = v.x * sc[k]     + sh[k];
    hb[k + 1] = v.y * sc[k + 1] + sh[k + 1];
    hb[k + 2] = v.z * sc[k + 2] + sh[k + 2];
    hb[k + 3] = v.w * sc[k + 3] + sh[k + 3];
  }
  float po[FH], ro[FH];
#pragma unroll
  for (int j = 0; j < FH; j++) {
    float a = 0.f, b = 0.f;
#pragma unroll
    for (int k = 0; k < FH; k++) {
      a += sWl[j * FH + k] * hb[k];
      b += sWr[j * FH + k] * hb[k];
    }
    po[j] = a; ro[j] = b;
  }
#pragma unroll
  for (int j = 0; j < FH; j += 4) {
    *(float4*)(p2 + n * FH + j) = make_float4(po[j], po[j + 1], po[j + 2], po[j + 3]);
    *(float4*)(r2 + n * FH + j) = make_float4(ro[j], ro[j + 1], ro[j + 2], ro[j + 3]);
  }
}

// ---------------------------------------------------------------------------
// conv2pool: h2 = relu(agg2/deg + r2 + b2), then graph mean-pool accumulate.
// batch is SORTED -> most waves graph-uniform: shuffle-reduce then one atomic
// set per wave (64x fewer atomics). Padding waves (all n>=NN) have ub==-1 and
// MUST be excluded: ub<0 guard (round-2 bug: OOB atomic corrupted gsum[4095]).
// ---------------------------------------------------------------------------
__global__ __launch_bounds__(256) void conv2pool_kernel(
    const float* __restrict__ agg2, const float* __restrict__ r2,
    const float* __restrict__ deg, const int* __restrict__ batch,
    const float* __restrict__ b2,
    float* __restrict__ gsum, float* __restrict__ gcnt) {
  __shared__ float sb[FH];
  int t = threadIdx.x;
  if (t < FH) sb[t] = b2[t];
  __syncthreads();

  int n = blockIdx.x * 256 + t;
  float h[FH];
  int b = -1;
  if (n < NN) {
    float invd = 1.0f / fmaxf(deg[n], 1.0f);
#pragma unroll
    for (int k = 0; k < FH; k += 4) {
      float4 av = *(const float4*)(agg2 + n * FH + k);
      float4 rv = *(const float4*)(r2 + n * FH + k);
      h[k]     = fmaxf(av.x * invd + rv.x + sb[k], 0.f);
      h[k + 1] = fmaxf(av.y * invd + rv.y + sb[k + 1], 0.f);
      h[k + 2] = fmaxf(av.z * invd + rv.z + sb[k + 2], 0.f);
      h[k + 3] = fmaxf(av.w * invd + rv.w + sb[k + 3], 0.f);
    }
    b = batch[n];
  } else {
#pragma unroll
    for (int j = 0; j < FH; j++) h[j] = 0.0f;
  }

  int ub = __shfl(b, 0);
  bool uniform = __all(b == ub);
  if (uniform && ub >= 0) {
#pragma unroll
    for (int j = 0; j < FH; j++) {
      float s = h[j];
      for (int off = 32; off; off >>= 1) s += __shfl_xor(s, off);
      h[j] = s;
    }
    if ((t & 63) == 0) {
#pragma unroll
      for (int j = 0; j < FH; j++) atomicAdd(gsum + ub * FH + j, h[j]);
      atomicAdd(gcnt + ub, 64.0f);
    }
  } else if (n < NN) {
#pragma unroll
    for (int j = 0; j < FH; j++) atomicAdd(gsum + b * FH + j, h[j]);
    atomicAdd(gcnt + b, 1.0f);
  }
}

// ---------------------------------------------------------------------------
// head: whole D2RL dense head in one block (G=256 rows).
// ---------------------------------------------------------------------------
__global__ __launch_bounds__(256) void head_kernel(
    const float* __restrict__ gsum, const float* __restrict__ gcnt,
    const float* __restrict__ gn1, const float* __restrict__ bn1,
    const float* __restrict__ Wl1, const float* __restrict__ bl1,
    const float* __restrict__ gn2, const float* __restrict__ bn2,
    const float* __restrict__ Wl2, const float* __restrict__ bl2,
    const float* __restrict__ gn3, const float* __restrict__ bn3,
    const float* __restrict__ Wl3, const float* __restrict__ bl3,
    const float* __restrict__ Wout, const float* __restrict__ bout,
    float* __restrict__ out) {
  __shared__ float sxe[FH * NG];   // x_enc, column-major [channel][graph]
  __shared__ float sz[FH * NG];    // z1
  __shared__ float sz2[FH * NG];   // z2
  __shared__ float sc1[FH], sh1[FH], sc2[2 * FH], sh2[2 * FH], sc3[2 * FH], sh3[2 * FH];

  int g = threadIdx.x;
  float cnt = fmaxf(gcnt[g], 1.0f);
  float xe[FH];
#pragma unroll
  for (int c = 0; c < FH; c++) {
    xe[c] = gsum[g * FH + c] / cnt;
    sxe[c * NG + g] = xe[c];
  }
  __syncthreads();

  if (g < FH) {
    float s = 0.f, q = 0.f;
    for (int i = 0; i < NG; i++) {
      float v = sxe[g * NG + i];
      s += v; q += v * v;
    }
    float m = s * (1.0f / NG);
    float var = q * (1.0f / NG) - m * m;
    float sc = gn1[g] * rsqrtf(var + EPS);
    sc1[g] = sc;
    sh1[g] = bn1[g] - m * sc;
  }
  __syncthreads();

  float z1[FH];
  {
    float xb[FH];
#pragma unroll
    for (int k = 0; k < FH; k++) xb[k] = xe[k] * sc1[k] + sh1[k];
#pragma unroll
    for (int j = 0; j < FH; j++) {
      float acc = bl1[j];
#pragma unroll
      for (int k = 0; k < FH; k++) acc += Wl1[j * FH + k] * xb[k];
      z1[j] = fmaxf(acc, 0.f);
      sz[j * NG + g] = z1[j];
    }
  }
  __syncthreads();

  if (g < 2 * FH) {
    const float* col = (g < FH) ? (sz + g * NG) : (sxe + (g - FH) * NG);
    float s = 0.f, q = 0.f;
    for (int i = 0; i < NG; i++) {
      float v = col[i];
      s += v; q += v * v;
    }
    float m = s * (1.0f / NG);
    float var = q * (1.0f / NG) - m * m;
    float sc = gn2[g] * rsqrtf(var + EPS);
    sc2[g] = sc;
    sh2[g] = bn2[g] - m * sc;
  }
  __syncthreads();

  float z2[FH];
  {
    float cat[2 * FH];
#pragma unroll
    for (int k = 0; k < FH; k++) {
      cat[k] = z1[k] * sc2[k] + sh2[k];
      cat[FH + k] = xe[k] * sc2[FH + k] + sh2[FH + k];
    }
#pragma unroll
    for (int j = 0; j < FH; j++) {
      float acc = bl2[j];
#pragma unroll
      for (int k = 0; k < 2 * FH; k++) acc += Wl2[j * 2 * FH + k] * cat[k];
      z2[j] = fmaxf(acc, 0.f);
      sz2[j * NG + g] = z2[j];
    }
  }
  __syncthreads();

  if (g < 2 * FH) {
    const float* col = (g < FH) ? (sz2 + g * NG) : (sxe + (g - FH) * NG);
    float s = 0.f, q = 0.f;
    for (int i = 0; i < NG; i++) {
      float v = col[i];
      s += v; q += v * v;
    }
    float m = s * (1.0f / NG);
    float var = q * (1.0f / NG) - m * m;
    float sc = gn3[g] * rsqrtf(var + EPS);
    sc3[g] = sc;
    sh3[g] = bn3[g] - m * sc;
  }
  __syncthreads();

  {
    float cat[2 * FH];
#pragma unroll
    for (int k = 0; k < FH; k++) {
      cat[k] = z2[k] * sc3[k] + sh3[k];
      cat[FH + k] = xe[k] * sc3[FH + k] + sh3[FH + k];
    }
    float o = bout[0];
#pragma unroll
    for (int j = 0; j < FH; j++) {
      float acc = bl3[j];
#pragma unroll
      for (int k = 0; k < 2 * FH; k++) acc += Wl3[j * 2 * FH + k] * cat[k];
      o += Wout[j] * fmaxf(acc, 0.f);
    }
    out[g] = o;
  }
}

// ---------------------------------------------------------------------------
extern "C" void kernel_launch(void* const* d_in, const int* in_sizes, int n_in,
                              void* d_out, int out_size, void* d_ws, size_t ws_size,
                              hipStream_t stream) {
  const float* x    = (const float*)d_in[0];
  const int*   ei   = (const int*)d_in[1];
  const int*   batch= (const int*)d_in[2];
  const float* W1l  = (const float*)d_in[3];
  const float* W1r  = (const float*)d_in[4];
  const float* b1   = (const float*)d_in[5];
  const float* g1   = (const float*)d_in[6];
  const float* be1  = (const float*)d_in[7];
  const float* W2l  = (const float*)d_in[8];
  const float* W2r  = (const float*)d_in[9];
  const float* b2   = (const float*)d_in[10];
  const float* gn1  = (const float*)d_in[11];
  const float* bn1  = (const float*)d_in[12];
  const float* Wl1  = (const float*)d_in[13];
  const float* bl1  = (const float*)d_in[14];
  const float* gn2  = (const float*)d_in[15];
  const float* bn2  = (const float*)d_in[16];
  const float* Wl2  = (const float*)d_in[17];
  const float* bl2  = (const float*)d_in[18];
  const float* gn3  = (const float*)d_in[19];
  const float* bn3  = (const float*)d_in[20];
  const float* Wl3  = (const float*)d_in[21];
  const float* bl3  = (const float*)d_in[22];
  const float* Wout = (const float*)d_in[23];
  const float* bout = (const float*)d_in[24];

  float* ws = (float*)d_ws;
  // zeroed region (one contiguous memset):
  float* deg   = ws;                                  // [N]
  float* aggP  = ws + NN;                             // [N*16]
  float* agg2  = ws + (size_t)NN * 17;                // [N*16]
  float* stats = ws + (size_t)NN * 33;                // sum16 sumsq16 sc16 sh16
  float* gsum  = stats + 64;                          // [G*16]
  float* gcnt  = gsum + NG * FH;                      // [G]
  // non-zeroed region:
  float* y1    = gcnt + NG;                           // [N*16] (reused: p2)
  float* r1    = y1 + (size_t)NN * FH;                // [N*16] (reused: r2)
  float* h1    = r1 + (size_t)NN * FH;                // [N*16]
  float* p2    = y1;
  float* r2    = r1;

  size_t zeroBytes = ((size_t)NN * 33 + 64 + (size_t)NG * (FH + 1)) * sizeof(float);
  hipMemsetAsync(d_ws, 0, zeroBytes, stream);

  int nodeBlocks = (NN + 255) / 256;
  int edgeBlocks = (NE * 4 + 255) / 256;

  proj1_kernel<<<nodeBlocks, 256, 0, stream>>>(x, W1l, W1r, y1, r1);
  agg_kernel<true><<<edgeBlocks, 256, 0, stream>>>(y1, ei, aggP, deg);
  conv1_kernel<<<nodeBlocks, 256, 0, stream>>>(aggP, r1, deg, b1, h1, stats);
  bn1_params_kernel<<<1, 64, 0, stream>>>(stats, g1, be1, stats + 32);
  proj2_kernel<<<nodeBlocks, 256, 0, stream>>>(h1, stats + 32, W2l, W2r, p2, r2);
  agg_kernel<false><<<edgeBlocks, 256, 0, stream>>>(p2, ei, agg2, nullptr);
  conv2pool_kernel<<<nodeBlocks, 256, 0, stream>>>(agg2, r2, deg, batch, b2, gsum, gcnt);
  head_kernel<<<1, 256, 0, stream>>>(gsum, gcnt, gn1, bn1, Wl1, bl1,
                                     gn2, bn2, Wl2, bl2, gn3, bn3, Wl3, bl3,
                                     Wout, bout, (float*)d_out);
}

// Round 4
// 674.267 us; speedup vs baseline: 1.8772x; 1.8772x over previous
//
#include <hip/hip_runtime.h>
#include <hip/hip_bf16.h>

#define NN 100000
#define NE 1600000
#define FIN 32
#define FH 16
#define NG 256
#define EPS 1e-5f
#define SCAN_T 1024
#define CHUNK 98  // ceil(NN / SCAN_T)

// ---------------------------------------------------------------------------
// CSR build, pass 1: in-degree histogram. 1.6M int atomics spread over 6250
// cache lines -> throughput-bound, unlike the old 25.6M f32 write-through.
// ---------------------------------------------------------------------------
__global__ __launch_bounds__(256) void hist_kernel(const int* __restrict__ ei,
                                                   int* __restrict__ degi) {
  int e = blockIdx.x * 256 + threadIdx.x;
  if (e < NE) atomicAdd(&degi[ei[NE + e]], 1);
}

// ---------------------------------------------------------------------------
// CSR build, pass 2: exclusive scan of degi -> row_ptr, plus cursor copy.
// One block, 1024 threads, 98 elements each + LDS scan of 1024 partials.
// ---------------------------------------------------------------------------
__global__ __launch_bounds__(1024) void scan_kernel(const int* __restrict__ degi,
                                                    int* __restrict__ row_ptr,
                                                    int* __restrict__ cursor) {
  __shared__ int part[SCAN_T];
  int t = threadIdx.x;
  int lo = t * CHUNK;
  int hi = min(lo + CHUNK, NN);
  int s = 0;
  for (int i = lo; i < hi; i++) s += degi[i];
  part[t] = s;
  __syncthreads();
  for (int off = 1; off < SCAN_T; off <<= 1) {
    int v = (t >= off) ? part[t - off] : 0;
    __syncthreads();
    part[t] += v;
    __syncthreads();
  }
  int base = (t > 0) ? part[t - 1] : 0;
  for (int i = lo; i < hi; i++) {
    row_ptr[i] = base;
    cursor[i] = base;
    base += degi[i];
  }
  if (t == 0) row_ptr[NN] = part[SCAN_T - 1];
}

// ---------------------------------------------------------------------------
// CSR build, pass 3: scatter src ids into per-dst slots.
// ---------------------------------------------------------------------------
__global__ __launch_bounds__(256) void scatter_kernel(const int* __restrict__ ei,
                                                      int* __restrict__ cursor,
                                                      int* __restrict__ csr_src) {
  int e = blockIdx.x * 256 + threadIdx.x;
  if (e >= NE) return;
  int src = ei[e];
  int dst = ei[NE + e];
  int pos = atomicAdd(&cursor[dst], 1);
  csr_src[pos] = src;
}

// ---------------------------------------------------------------------------
// proj1: y1 = x @ W1l.T, r1 = x @ W1r.T (projection BEFORE aggregation:
// linear map commutes with segment_sum; gathers run in 16-dim space).
// ---------------------------------------------------------------------------
__global__ __launch_bounds__(256) void proj1_kernel(
    const float* __restrict__ x,
    const float* __restrict__ W1l, const float* __restrict__ W1r,
    float* __restrict__ y1, float* __restrict__ r1) {
  __shared__ float sWl[FH * FIN];
  __shared__ float sWr[FH * FIN];
  int t = threadIdx.x;
  for (int i = t; i < FH * FIN; i += 256) {
    sWl[i] = W1l[i];
    sWr[i] = W1r[i];
  }
  __syncthreads();

  int n = blockIdx.x * 256 + t;
  if (n >= NN) return;
  float xl[FIN];
#pragma unroll
  for (int k = 0; k < FIN; k += 4) {
    float4 v = *(const float4*)(x + n * FIN + k);
    xl[k] = v.x; xl[k + 1] = v.y; xl[k + 2] = v.z; xl[k + 3] = v.w;
  }
  float yo[FH], ro[FH];
#pragma unroll
  for (int j = 0; j < FH; j++) {
    float a = 0.f, b = 0.f;
#pragma unroll
    for (int k = 0; k < FIN; k++) {
      a += sWl[j * FIN + k] * xl[k];
      b += sWr[j * FIN + k] * xl[k];
    }
    yo[j] = a; ro[j] = b;
  }
#pragma unroll
  for (int j = 0; j < FH; j += 4) {
    *(float4*)(y1 + n * FH + j) = make_float4(yo[j], yo[j + 1], yo[j + 2], yo[j + 3]);
    *(float4*)(r1 + n * FH + j) = make_float4(ro[j], ro[j + 1], ro[j + 2], ro[j + 3]);
  }
}

// ---------------------------------------------------------------------------
// sage1: gather-based conv1. 4 lanes/node, each owns a channel quad.
// h1 = relu(gather_mean(y1) + r1 + b1). BN stats -> per-block partials
// (NO global atomics: round-3 lesson — 50K atomics on 2 lines serialize).
// ---------------------------------------------------------------------------
__global__ __launch_bounds__(256) void sage1_kernel(
    const int* __restrict__ row_ptr, const int* __restrict__ csr_src,
    const float* __restrict__ y1, const float* __restrict__ r1,
    const float* __restrict__ b1,
    float* __restrict__ h1, float* __restrict__ partials) {
  __shared__ float sstat[4][32];
  int t = threadIdx.x;
  int gid = blockIdx.x * 256 + t;
  int n = gid >> 2;
  int c = gid & 3;  // == t&3, so lanes 0..3 of each wave have c == lane id

  float h[4] = {0.f, 0.f, 0.f, 0.f};
  if (n < NN) {
    int beg = row_ptr[n], end = row_ptr[n + 1];
    float invd = 1.0f / (float)max(end - beg, 1);
    float4 acc = make_float4(0.f, 0.f, 0.f, 0.f);
    int i = beg;
    for (; i + 1 < end; i += 2) {  // unroll-2 for memory-level parallelism
      int s0 = csr_src[i], s1 = csr_src[i + 1];
      float4 v0 = *(const float4*)(y1 + s0 * FH + c * 4);
      float4 v1 = *(const float4*)(y1 + s1 * FH + c * 4);
      acc.x += v0.x + v1.x; acc.y += v0.y + v1.y;
      acc.z += v0.z + v1.z; acc.w += v0.w + v1.w;
    }
    if (i < end) {
      float4 v0 = *(const float4*)(y1 + csr_src[i] * FH + c * 4);
      acc.x += v0.x; acc.y += v0.y; acc.z += v0.z; acc.w += v0.w;
    }
    float4 rv = *(const float4*)(r1 + n * FH + c * 4);
    float4 bv = *(const float4*)(b1 + c * 4);
    h[0] = fmaxf(acc.x * invd + rv.x + bv.x, 0.f);
    h[1] = fmaxf(acc.y * invd + rv.y + bv.y, 0.f);
    h[2] = fmaxf(acc.z * invd + rv.z + bv.z, 0.f);
    h[3] = fmaxf(acc.w * invd + rv.w + bv.w, 0.f);
    *(float4*)(h1 + n * FH + c * 4) = make_float4(h[0], h[1], h[2], h[3]);
  }

  // reduce s,q over the 16 lanes sharing this c (stride-4 groups)
  float s[4], q[4];
#pragma unroll
  for (int j = 0; j < 4; j++) { s[j] = h[j]; q[j] = h[j] * h[j]; }
#pragma unroll
  for (int off = 4; off < 64; off <<= 1) {
#pragma unroll
    for (int j = 0; j < 4; j++) {
      s[j] += __shfl_xor(s[j], off);
      q[j] += __shfl_xor(q[j], off);
    }
  }
  int t6 = t & 63, w = t >> 6;
  if (t6 < 4) {
#pragma unroll
    for (int j = 0; j < 4; j++) {
      sstat[w][t6 * 4 + j] = s[j];
      sstat[w][16 + t6 * 4 + j] = q[j];
    }
  }
  __syncthreads();
  if (t < 32)
    partials[blockIdx.x * 32 + t] =
        sstat[0][t] + sstat[1][t] + sstat[2][t] + sstat[3][t];
}

// ---------------------------------------------------------------------------
// bn1_params: reduce per-block partials (P blocks x 32) then finalize BN1
// scale/shift. One block, no atomics.
// ---------------------------------------------------------------------------
__global__ __launch_bounds__(1024) void bn1_params_kernel(
    const float* __restrict__ partials, int P,
    const float* __restrict__ g1, const float* __restrict__ be1,
    float* __restrict__ scsh) {
  __shared__ float red[32][33];
  __shared__ float tot[32];
  int t = threadIdx.x;
  int ch = t & 31, seg = t >> 5;
  float s = 0.f;
  for (int b = seg; b < P; b += 32) s += partials[b * 32 + ch];
  red[seg][ch] = s;
  __syncthreads();
  if (t < 32) {
    float v = 0.f;
    for (int k = 0; k < 32; k++) v += red[k][t];
    tot[t] = v;
  }
  __syncthreads();
  if (t < FH) {
    float m = tot[t] * (1.0f / NN);
    float var = tot[FH + t] * (1.0f / NN) - m * m;
    float sc = g1[t] * rsqrtf(var + EPS);
    scsh[t] = sc;
    scsh[FH + t] = be1[t] - m * sc;
  }
}

// ---------------------------------------------------------------------------
// proj2: hb = bn1(h1) on the fly, p2 = hb @ W2l.T, r2 = hb @ W2r.T.
// ---------------------------------------------------------------------------
__global__ __launch_bounds__(256) void proj2_kernel(
    const float* __restrict__ h1, const float* __restrict__ scsh,
    const float* __restrict__ W2l, const float* __restrict__ W2r,
    float* __restrict__ p2, float* __restrict__ r2) {
  __shared__ float sWl[FH * FH];
  __shared__ float sWr[FH * FH];
  __shared__ float sc[FH], sh[FH];
  int t = threadIdx.x;
  if (t < FH * FH) {
    sWl[t] = W2l[t];
    sWr[t] = W2r[t];
  }
  if (t < FH) {
    sc[t] = scsh[t];
    sh[t] = scsh[FH + t];
  }
  __syncthreads();

  int n = blockIdx.x * 256 + t;
  if (n >= NN) return;
  float hb[FH];
#pragma unroll
  for (int k = 0; k < FH; k += 4) {
    float4 v = *(const float4*)(h1 + n * FH + k);
    hb[k]     = v.x * sc[k]     + sh[k];
    hb[k + 1] = v.y * sc[k + 1] + sh[k + 1];
    hb[k + 2] = v.z * sc[k + 2] + sh[k + 2];
    hb[k + 3] = v.w * sc[k + 3] + sh[k + 3];
  }
  float po[FH], ro[FH];
#pragma unroll
  for (int j = 0; j < FH; j++) {
    float a = 0.f, b = 0.f;
#pragma unroll
    for (int k = 0; k < FH; k++) {
      a += sWl[j * FH + k] * hb[k];
      b += sWr[j * FH + k] * hb[k];
    }
    po[j] = a; ro[j] = b;
  }
#pragma unroll
  for (int j = 0; j < FH; j += 4) {
    *(float4*)(p2 + n * FH + j) = make_float4(po[j], po[j + 1], po[j + 2], po[j + 3]);
    *(float4*)(r2 + n * FH + j) = make_float4(ro[j], ro[j + 1], ro[j + 2], ro[j + 3]);
  }
}

// ---------------------------------------------------------------------------
// sage2: gather-based conv2 + graph mean-pool. 4 lanes/node. batch sorted ->
// wave-uniform fast path (16 atomics/wave, each gsum row = one 64B line).
// ub>=0 guard excludes padding waves (round-2 OOB bug).
// ---------------------------------------------------------------------------
__global__ __launch_bounds__(256) void sage2_kernel(
    const int* __restrict__ row_ptr, const int* __restrict__ csr_src,
    const float* __restrict__ p2, const float* __restrict__ r2,
    const float* __restrict__ b2, const int* __restrict__ batch,
    float* __restrict__ gsum) {
  int t = threadIdx.x;
  int gid = blockIdx.x * 256 + t;
  int n = gid >> 2;
  int c = gid & 3;

  float h[4] = {0.f, 0.f, 0.f, 0.f};
  int b = -1;
  if (n < NN) {
    int beg = row_ptr[n], end = row_ptr[n + 1];
    float invd = 1.0f / (float)max(end - beg, 1);
    float4 acc = make_float4(0.f, 0.f, 0.f, 0.f);
    int i = beg;
    for (; i + 1 < end; i += 2) {
      int s0 = csr_src[i], s1 = csr_src[i + 1];
      float4 v0 = *(const float4*)(p2 + s0 * FH + c * 4);
      float4 v1 = *(const float4*)(p2 + s1 * FH + c * 4);
      acc.x += v0.x + v1.x; acc.y += v0.y + v1.y;
      acc.z += v0.z + v1.z; acc.w += v0.w + v1.w;
    }
    if (i < end) {
      float4 v0 = *(const float4*)(p2 + csr_src[i] * FH + c * 4);
      acc.x += v0.x; acc.y += v0.y; acc.z += v0.z; acc.w += v0.w;
    }
    float4 rv = *(const float4*)(r2 + n * FH + c * 4);
    float4 bv = *(const float4*)(b2 + c * 4);
    h[0] = fmaxf(acc.x * invd + rv.x + bv.x, 0.f);
    h[1] = fmaxf(acc.y * invd + rv.y + bv.y, 0.f);
    h[2] = fmaxf(acc.z * invd + rv.z + bv.z, 0.f);
    h[3] = fmaxf(acc.w * invd + rv.w + bv.w, 0.f);
    b = batch[n];
  }

  int ub = __shfl(b, 0);
  bool uniform = __all(b == ub);
  if (uniform && ub >= 0) {
#pragma unroll
    for (int off = 4; off < 64; off <<= 1)
#pragma unroll
      for (int j = 0; j < 4; j++) h[j] += __shfl_xor(h[j], off);
    if ((t & 63) < 4) {
#pragma unroll
      for (int j = 0; j < 4; j++) atomicAdd(gsum + ub * FH + c * 4 + j, h[j]);
    }
  } else if (n < NN) {
#pragma unroll
    for (int j = 0; j < 4; j++) atomicAdd(gsum + b * FH + c * 4 + j, h[j]);
  }
}

// ---------------------------------------------------------------------------
// head: whole D2RL dense head in one block. Per-graph counts via binary
// search on sorted batch (replaces gcnt atomics).
// ---------------------------------------------------------------------------
__global__ __launch_bounds__(256) void head_kernel(
    const float* __restrict__ gsum, const int* __restrict__ batch,
    const float* __restrict__ gn1, const float* __restrict__ bn1,
    const float* __restrict__ Wl1, const float* __restrict__ bl1,
    const float* __restrict__ gn2, const float* __restrict__ bn2,
    const float* __restrict__ Wl2, const float* __restrict__ bl2,
    const float* __restrict__ gn3, const float* __restrict__ bn3,
    const float* __restrict__ Wl3, const float* __restrict__ bl3,
    const float* __restrict__ Wout, const float* __restrict__ bout,
    float* __restrict__ out) {
  __shared__ float sxe[FH * NG];
  __shared__ float sz[FH * NG];
  __shared__ float sz2[FH * NG];
  __shared__ float sc1[FH], sh1[FH], sc2[2 * FH], sh2[2 * FH], sc3[2 * FH], sh3[2 * FH];

  int g = threadIdx.x;
  // count nodes in graph g: lower_bound(g), lower_bound(g+1) on sorted batch
  int lo = 0, hi = NN;
  while (lo < hi) { int mid = (lo + hi) >> 1; if (batch[mid] < g) lo = mid + 1; else hi = mid; }
  int lo2 = lo, hi2 = NN;
  while (lo2 < hi2) { int mid = (lo2 + hi2) >> 1; if (batch[mid] < g + 1) lo2 = mid + 1; else hi2 = mid; }
  float cnt = fmaxf((float)(lo2 - lo), 1.0f);

  float xe[FH];
#pragma unroll
  for (int c = 0; c < FH; c++) {
    xe[c] = gsum[g * FH + c] / cnt;
    sxe[c * NG + g] = xe[c];
  }
  __syncthreads();

  if (g < FH) {
    float s = 0.f, q = 0.f;
    for (int i = 0; i < NG; i++) {
      float v = sxe[g * NG + i];
      s += v; q += v * v;
    }
    float m = s * (1.0f / NG);
    float var = q * (1.0f / NG) - m * m;
    float sc = gn1[g] * rsqrtf(var + EPS);
    sc1[g] = sc;
    sh1[g] = bn1[g] - m * sc;
  }
  __syncthreads();

  float z1[FH];
  {
    float xb[FH];
#pragma unroll
    for (int k = 0; k < FH; k++) xb[k] = xe[k] * sc1[k] + sh1[k];
#pragma unroll
    for (int j = 0; j < FH; j++) {
      float acc = bl1[j];
#pragma unroll
      for (int k = 0; k < FH; k++) acc += Wl1[j * FH + k] * xb[k];
      z1[j] = fmaxf(acc, 0.f);
      sz[j * NG + g] = z1[j];
    }
  }
  __syncthreads();

  if (g < 2 * FH) {
    const float* col = (g < FH) ? (sz + g * NG) : (sxe + (g - FH) * NG);
    float s = 0.f, q = 0.f;
    for (int i = 0; i < NG; i++) {
      float v = col[i];
      s += v; q += v * v;
    }
    float m = s * (1.0f / NG);
    float var = q * (1.0f / NG) - m * m;
    float sc = gn2[g] * rsqrtf(var + EPS);
    sc2[g] = sc;
    sh2[g] = bn2[g] - m * sc;
  }
  __syncthreads();

  float z2[FH];
  {
    float cat[2 * FH];
#pragma unroll
    for (int k = 0; k < FH; k++) {
      cat[k] = z1[k] * sc2[k] + sh2[k];
      cat[FH + k] = xe[k] * sc2[FH + k] + sh2[FH + k];
    }
#pragma unroll
    for (int j = 0; j < FH; j++) {
      float acc = bl2[j];
#pragma unroll
      for (int k = 0; k < 2 * FH; k++) acc += Wl2[j * 2 * FH + k] * cat[k];
      z2[j] = fmaxf(acc, 0.f);
      sz2[j * NG + g] = z2[j];
    }
  }
  __syncthreads();

  if (g < 2 * FH) {
    const float* col = (g < FH) ? (sz2 + g * NG) : (sxe + (g - FH) * NG);
    float s = 0.f, q = 0.f;
    for (int i = 0; i < NG; i++) {
      float v = col[i];
      s += v; q += v * v;
    }
    float m = s * (1.0f / NG);
    float var = q * (1.0f / NG) - m * m;
    float sc = gn3[g] * rsqrtf(var + EPS);
    sc3[g] = sc;
    sh3[g] = bn3[g] - m * sc;
  }
  __syncthreads();

  {
    float cat[2 * FH];
#pragma unroll
    for (int k = 0; k < FH; k++) {
      cat[k] = z2[k] * sc3[k] + sh3[k];
      cat[FH + k] = xe[k] * sc3[FH + k] + sh3[FH + k];
    }
    float o = bout[0];
#pragma unroll
    for (int j = 0; j < FH; j++) {
      float acc = bl3[j];
#pragma unroll
      for (int k = 0; k < 2 * FH; k++) acc += Wl3[j * 2 * FH + k] * cat[k];
      o += Wout[j] * fmaxf(acc, 0.f);
    }
    out[g] = o;
  }
}

// ---------------------------------------------------------------------------
extern "C" void kernel_launch(void* const* d_in, const int* in_sizes, int n_in,
                              void* d_out, int out_size, void* d_ws, size_t ws_size,
                              hipStream_t stream) {
  const float* x    = (const float*)d_in[0];
  const int*   ei   = (const int*)d_in[1];
  const int*   batch= (const int*)d_in[2];
  const float* W1l  = (const float*)d_in[3];
  const float* W1r  = (const float*)d_in[4];
  const float* b1   = (const float*)d_in[5];
  const float* g1   = (const float*)d_in[6];
  const float* be1  = (const float*)d_in[7];
  const float* W2l  = (const float*)d_in[8];
  const float* W2r  = (const float*)d_in[9];
  const float* b2   = (const float*)d_in[10];
  const float* gn1  = (const float*)d_in[11];
  const float* bn1  = (const float*)d_in[12];
  const float* Wl1  = (const float*)d_in[13];
  const float* bl1  = (const float*)d_in[14];
  const float* gn2  = (const float*)d_in[15];
  const float* bn2  = (const float*)d_in[16];
  const float* Wl2  = (const float*)d_in[17];
  const float* bl2  = (const float*)d_in[18];
  const float* gn3  = (const float*)d_in[19];
  const float* bn3  = (const float*)d_in[20];
  const float* Wl3  = (const float*)d_in[21];
  const float* bl3  = (const float*)d_in[22];
  const float* Wout = (const float*)d_in[23];
  const float* bout = (const float*)d_in[24];

  const int sageBlocks = (NN * 4 + 255) / 256;  // 1563

  int* wi = (int*)d_ws;
  // zeroed region:
  int*   degi    = wi;                          // [NN]
  float* gsum    = (float*)(wi + NN);           // [NG*FH] = 4096
  // non-zeroed:
  int*   row_ptr = wi + NN + NG * FH;           // [NN+1]
  int*   cursor  = row_ptr + NN + 1;            // [NN]
  int*   csr_src = cursor + NN;                 // [NE]
  float* partials= (float*)(csr_src + NE);      // [sageBlocks*32]
  float* scsh    = partials + sageBlocks * 32;  // [32]
  float* y1      = scsh + 32;                   // [NN*16] (reused as p2)
  float* r1      = y1 + NN * FH;                // [NN*16] (reused as r2)
  float* h1      = r1 + NN * FH;                // [NN*16]
  float* p2      = y1;
  float* r2      = r1;

  hipMemsetAsync(d_ws, 0, (size_t)(NN + NG * FH) * sizeof(int), stream);

  int nodeBlocks = (NN + 255) / 256;
  int edgeBlocks = (NE + 255) / 256;

  hist_kernel<<<edgeBlocks, 256, 0, stream>>>(ei, degi);
  scan_kernel<<<1, SCAN_T, 0, stream>>>(degi, row_ptr, cursor);
  scatter_kernel<<<edgeBlocks, 256, 0, stream>>>(ei, cursor, csr_src);
  proj1_kernel<<<nodeBlocks, 256, 0, stream>>>(x, W1l, W1r, y1, r1);
  sage1_kernel<<<sageBlocks, 256, 0, stream>>>(row_ptr, csr_src, y1, r1, b1, h1, partials);
  bn1_params_kernel<<<1, 1024, 0, stream>>>(partials, sageBlocks, g1, be1, scsh);
  proj2_kernel<<<nodeBlocks, 256, 0, stream>>>(h1, scsh, W2l, W2r, p2, r2);
  sage2_kernel<<<sageBlocks, 256, 0, stream>>>(row_ptr, csr_src, p2, r2, b2, batch, gsum);
  head_kernel<<<1, 256, 0, stream>>>(gsum, batch, gn1, bn1, Wl1, bl1,
                                     gn2, bn2, Wl2, bl2, gn3, bn3, Wl3, bl3,
                                     Wout, bout, (float*)d_out);
}

// Round 6
// 442.703 us; speedup vs baseline: 2.8591x; 1.5231x over previous
//
#include <hip/hip_runtime.h>
#include <hip/hip_bf16.h>

#define NN 100000
#define NE 1600000
#define FIN 32
#define FH 16
#define NG 256
#define EPS 1e-5f
#define SCHUNK 512
#define NSB ((NN + SCHUNK - 1) / SCHUNK)  // 196 scan blocks

// ---------------------------------------------------------------------------
// CSR build, pass 1: in-degree histogram. 1.6M int atomics spread over 6250
// cache lines -> throughput-bound.
// ---------------------------------------------------------------------------
__global__ __launch_bounds__(256) void hist_kernel(const int* __restrict__ ei,
                                                   int* __restrict__ degi) {
  int e = blockIdx.x * 256 + threadIdx.x;
  if (e < NE) atomicAdd(&degi[ei[NE + e]], 1);
}

// ---------------------------------------------------------------------------
// Scan phase 1: per-block reduce of 512 degi elements -> bsum[block].
// (round-4 lesson: the single-block 1024-thread scan was 230 us at 0.15%
// occupancy — latency-bound on one CU. 196 blocks saturate the grid.)
// ---------------------------------------------------------------------------
__global__ __launch_bounds__(256) void scan_reduce_kernel(
    const int* __restrict__ degi, int* __restrict__ bsum) {
  __shared__ int wsum[4];
  int t = threadIdx.x;
  int i0 = blockIdx.x * SCHUNK + t * 2;
  int d0 = (i0 < NN) ? degi[i0] : 0;
  int d1 = (i0 + 1 < NN) ? degi[i0 + 1] : 0;
  int s = d0 + d1;
  for (int off = 32; off; off >>= 1) s += __shfl_xor(s, off);
  if ((t & 63) == 0) wsum[t >> 6] = s;
  __syncthreads();
  if (t == 0) bsum[blockIdx.x] = wsum[0] + wsum[1] + wsum[2] + wsum[3];
}

// ---------------------------------------------------------------------------
// Scan phase 2: one block scans the 196 block sums -> exclusive bpre[],
// and writes row_ptr[NN] = total.
// ---------------------------------------------------------------------------
__global__ __launch_bounds__(256) void scan_mid_kernel(
    const int* __restrict__ bsum, int* __restrict__ bpre,
    int* __restrict__ row_ptr) {
  __shared__ int part[256];
  int t = threadIdx.x;
  int v = (t < NSB) ? bsum[t] : 0;
  part[t] = v;
  __syncthreads();
  for (int off = 1; off < 256; off <<= 1) {
    int u = (t >= off) ? part[t - off] : 0;
    __syncthreads();
    part[t] += u;
    __syncthreads();
  }
  if (t < NSB) bpre[t] = part[t] - v;  // exclusive
  if (t == 255) row_ptr[NN] = part[255];
}

// ---------------------------------------------------------------------------
// Scan phase 3: per-block local exclusive scan + block prefix -> row_ptr,
// cursor. Coalesced.
// ---------------------------------------------------------------------------
__global__ __launch_bounds__(256) void scan_out_kernel(
    const int* __restrict__ degi, const int* __restrict__ bpre,
    int* __restrict__ row_ptr, int* __restrict__ cursor) {
  __shared__ int part[256];
  int t = threadIdx.x;
  int i0 = blockIdx.x * SCHUNK + t * 2;
  int d0 = (i0 < NN) ? degi[i0] : 0;
  int d1 = (i0 + 1 < NN) ? degi[i0 + 1] : 0;
  int ts = d0 + d1;
  part[t] = ts;
  __syncthreads();
  for (int off = 1; off < 256; off <<= 1) {
    int u = (t >= off) ? part[t - off] : 0;
    __syncthreads();
    part[t] += u;
    __syncthreads();
  }
  int base = bpre[blockIdx.x] + part[t] - ts;
  if (i0 < NN) { row_ptr[i0] = base; cursor[i0] = base; }
  if (i0 + 1 < NN) { row_ptr[i0 + 1] = base + d0; cursor[i0 + 1] = base + d0; }
}

// ---------------------------------------------------------------------------
// CSR build, pass 3: scatter src ids into per-dst slots.
// ---------------------------------------------------------------------------
__global__ __launch_bounds__(256) void scatter_kernel(const int* __restrict__ ei,
                                                      int* __restrict__ cursor,
                                                      int* __restrict__ csr_src) {
  int e = blockIdx.x * 256 + threadIdx.x;
  if (e >= NE) return;
  int src = ei[e];
  int dst = ei[NE + e];
  int pos = atomicAdd(&cursor[dst], 1);
  csr_src[pos] = src;
}

// ---------------------------------------------------------------------------
// proj1: y1 = x @ W1l.T, r1 = x @ W1r.T (projection BEFORE aggregation:
// linear map commutes with segment_sum; gathers run in 16-dim space).
// ---------------------------------------------------------------------------
__global__ __launch_bounds__(256) void proj1_kernel(
    const float* __restrict__ x,
    const float* __restrict__ W1l, const float* __restrict__ W1r,
    float* __restrict__ y1, float* __restrict__ r1) {
  __shared__ float sWl[FH * FIN];
  __shared__ float sWr[FH * FIN];
  int t = threadIdx.x;
  for (int i = t; i < FH * FIN; i += 256) {
    sWl[i] = W1l[i];
    sWr[i] = W1r[i];
  }
  __syncthreads();

  int n = blockIdx.x * 256 + t;
  if (n >= NN) return;
  float xl[FIN];
#pragma unroll
  for (int k = 0; k < FIN; k += 4) {
    float4 v = *(const float4*)(x + n * FIN + k);
    xl[k] = v.x; xl[k + 1] = v.y; xl[k + 2] = v.z; xl[k + 3] = v.w;
  }
  float yo[FH], ro[FH];
#pragma unroll
  for (int j = 0; j < FH; j++) {
    float a = 0.f, b = 0.f;
#pragma unroll
    for (int k = 0; k < FIN; k++) {
      a += sWl[j * FIN + k] * xl[k];
      b += sWr[j * FIN + k] * xl[k];
    }
    yo[j] = a; ro[j] = b;
  }
#pragma unroll
  for (int j = 0; j < FH; j += 4) {
    *(float4*)(y1 + n * FH + j) = make_float4(yo[j], yo[j + 1], yo[j + 2], yo[j + 3]);
    *(float4*)(r1 + n * FH + j) = make_float4(ro[j], ro[j + 1], ro[j + 2], ro[j + 3]);
  }
}

// ---------------------------------------------------------------------------
// sage1: gather-based conv1. 4 lanes/node, each owns a channel quad.
// h1 = relu(gather_mean(y1) + r1 + b1). BN stats -> per-block partials.
// ---------------------------------------------------------------------------
__global__ __launch_bounds__(256) void sage1_kernel(
    const int* __restrict__ row_ptr, const int* __restrict__ csr_src,
    const float* __restrict__ y1, const float* __restrict__ r1,
    const float* __restrict__ b1,
    float* __restrict__ h1, float* __restrict__ partials) {
  __shared__ float sstat[4][32];
  int t = threadIdx.x;
  int gid = blockIdx.x * 256 + t;
  int n = gid >> 2;
  int c = gid & 3;

  float h[4] = {0.f, 0.f, 0.f, 0.f};
  if (n < NN) {
    int beg = row_ptr[n], end = row_ptr[n + 1];
    float invd = 1.0f / (float)max(end - beg, 1);
    float4 acc = make_float4(0.f, 0.f, 0.f, 0.f);
    int i = beg;
    for (; i + 1 < end; i += 2) {
      int s0 = csr_src[i], s1 = csr_src[i + 1];
      float4 v0 = *(const float4*)(y1 + s0 * FH + c * 4);
      float4 v1 = *(const float4*)(y1 + s1 * FH + c * 4);
      acc.x += v0.x + v1.x; acc.y += v0.y + v1.y;
      acc.z += v0.z + v1.z; acc.w += v0.w + v1.w;
    }
    if (i < end) {
      float4 v0 = *(const float4*)(y1 + csr_src[i] * FH + c * 4);
      acc.x += v0.x; acc.y += v0.y; acc.z += v0.z; acc.w += v0.w;
    }
    float4 rv = *(const float4*)(r1 + n * FH + c * 4);
    float4 bv = *(const float4*)(b1 + c * 4);
    h[0] = fmaxf(acc.x * invd + rv.x + bv.x, 0.f);
    h[1] = fmaxf(acc.y * invd + rv.y + bv.y, 0.f);
    h[2] = fmaxf(acc.z * invd + rv.z + bv.z, 0.f);
    h[3] = fmaxf(acc.w * invd + rv.w + bv.w, 0.f);
    *(float4*)(h1 + n * FH + c * 4) = make_float4(h[0], h[1], h[2], h[3]);
  }

  float s[4], q[4];
#pragma unroll
  for (int j = 0; j < 4; j++) { s[j] = h[j]; q[j] = h[j] * h[j]; }
#pragma unroll
  for (int off = 4; off < 64; off <<= 1) {
#pragma unroll
    for (int j = 0; j < 4; j++) {
      s[j] += __shfl_xor(s[j], off);
      q[j] += __shfl_xor(q[j], off);
    }
  }
  int t6 = t & 63, w = t >> 6;
  if (t6 < 4) {
#pragma unroll
    for (int j = 0; j < 4; j++) {
      sstat[w][t6 * 4 + j] = s[j];
      sstat[w][16 + t6 * 4 + j] = q[j];
    }
  }
  __syncthreads();
  if (t < 32)
    partials[blockIdx.x * 32 + t] =
        sstat[0][t] + sstat[1][t] + sstat[2][t] + sstat[3][t];
}

// ---------------------------------------------------------------------------
// bn1_params: reduce per-block partials then finalize BN1 scale/shift.
// ---------------------------------------------------------------------------
__global__ __launch_bounds__(1024) void bn1_params_kernel(
    const float* __restrict__ partials, int P,
    const float* __restrict__ g1, const float* __restrict__ be1,
    float* __restrict__ scsh) {
  __shared__ float red[32][33];
  __shared__ float tot[32];
  int t = threadIdx.x;
  int ch = t & 31, seg = t >> 5;
  float s = 0.f;
  for (int b = seg; b < P; b += 32) s += partials[b * 32 + ch];
  red[seg][ch] = s;
  __syncthreads();
  if (t < 32) {
    float v = 0.f;
    for (int k = 0; k < 32; k++) v += red[k][t];
    tot[t] = v;
  }
  __syncthreads();
  if (t < FH) {
    float m = tot[t] * (1.0f / NN);
    float var = tot[FH + t] * (1.0f / NN) - m * m;
    float sc = g1[t] * rsqrtf(var + EPS);
    scsh[t] = sc;
    scsh[FH + t] = be1[t] - m * sc;
  }
}

// ---------------------------------------------------------------------------
// proj2: hb = bn1(h1) on the fly, p2 = hb @ W2l.T, r2 = hb @ W2r.T.
// ---------------------------------------------------------------------------
__global__ __launch_bounds__(256) void proj2_kernel(
    const float* __restrict__ h1, const float* __restrict__ scsh,
    const float* __restrict__ W2l, const float* __restrict__ W2r,
    float* __restrict__ p2, float* __restrict__ r2) {
  __shared__ float sWl[FH * FH];
  __shared__ float sWr[FH * FH];
  __shared__ float sc[FH], sh[FH];
  int t = threadIdx.x;
  if (t < FH * FH) {
    sWl[t] = W2l[t];
    sWr[t] = W2r[t];
  }
  if (t < FH) {
    sc[t] = scsh[t];
    sh[t] = scsh[FH + t];
  }
  __syncthreads();

  int n = blockIdx.x * 256 + t;
  if (n >= NN) return;
  float hb[FH];
#pragma unroll
  for (int k = 0; k < FH; k += 4) {
    float4 v = *(const float4*)(h1 + n * FH + k);
    hb[k]     = v.x * sc[k]     + sh[k];
    hb[k + 1] = v.y * sc[k + 1] + sh[k + 1];
    hb[k + 2] = v.z * sc[k + 2] + sh[k + 2];
    hb[k + 3] = v.w * sc[k + 3] + sh[k + 3];
  }
  float po[FH], ro[FH];
#pragma unroll
  for (int j = 0; j < FH; j++) {
    float a = 0.f, b = 0.f;
#pragma unroll
    for (int k = 0; k < FH; k++) {
      a += sWl[j * FH + k] * hb[k];
      b += sWr[j * FH + k] * hb[k];
    }
    po[j] = a; ro[j] = b;
  }
#pragma unroll
  for (int j = 0; j < FH; j += 4) {
    *(float4*)(p2 + n * FH + j) = make_float4(po[j], po[j + 1], po[j + 2], po[j + 3]);
    *(float4*)(r2 + n * FH + j) = make_float4(ro[j], ro[j + 1], ro[j + 2], ro[j + 3]);
  }
}

// ---------------------------------------------------------------------------
// sage2: gather-based conv2 + graph mean-pool. batch sorted -> wave-uniform
// fast path; ub>=0 guard excludes padding waves (round-2 OOB bug).
// ---------------------------------------------------------------------------
__global__ __launch_bounds__(256) void sage2_kernel(
    const int* __restrict__ row_ptr, const int* __restrict__ csr_src,
    const float* __restrict__ p2, const float* __restrict__ r2,
    const float* __restrict__ b2, const int* __restrict__ batch,
    float* __restrict__ gsum) {
  int t = threadIdx.x;
  int gid = blockIdx.x * 256 + t;
  int n = gid >> 2;
  int c = gid & 3;

  float h[4] = {0.f, 0.f, 0.f, 0.f};
  int b = -1;
  if (n < NN) {
    int beg = row_ptr[n], end = row_ptr[n + 1];
    float invd = 1.0f / (float)max(end - beg, 1);
    float4 acc = make_float4(0.f, 0.f, 0.f, 0.f);
    int i = beg;
    for (; i + 1 < end; i += 2) {
      int s0 = csr_src[i], s1 = csr_src[i + 1];
      float4 v0 = *(const float4*)(p2 + s0 * FH + c * 4);
      float4 v1 = *(const float4*)(p2 + s1 * FH + c * 4);
      acc.x += v0.x + v1.x; acc.y += v0.y + v1.y;
      acc.z += v0.z + v1.z; acc.w += v0.w + v1.w;
    }
    if (i < end) {
      float4 v0 = *(const float4*)(p2 + csr_src[i] * FH + c * 4);
      acc.x += v0.x; acc.y += v0.y; acc.z += v0.z; acc.w += v0.w;
    }
    float4 rv = *(const float4*)(r2 + n * FH + c * 4);
    float4 bv = *(const float4*)(b2 + c * 4);
    h[0] = fmaxf(acc.x * invd + rv.x + bv.x, 0.f);
    h[1] = fmaxf(acc.y * invd + rv.y + bv.y, 0.f);
    h[2] = fmaxf(acc.z * invd + rv.z + bv.z, 0.f);
    h[3] = fmaxf(acc.w * invd + rv.w + bv.w, 0.f);
    b = batch[n];
  }

  int ub = __shfl(b, 0);
  bool uniform = __all(b == ub);
  if (uniform && ub >= 0) {
#pragma unroll
    for (int off = 4; off < 64; off <<= 1)
#pragma unroll
      for (int j = 0; j < 4; j++) h[j] += __shfl_xor(h[j], off);
    if ((t & 63) < 4) {
#pragma unroll
      for (int j = 0; j < 4; j++) atomicAdd(gsum + ub * FH + c * 4 + j, h[j]);
    }
  } else if (n < NN) {
#pragma unroll
    for (int j = 0; j < 4; j++) atomicAdd(gsum + b * FH + c * 4 + j, h[j]);
  }
}

// ---------------------------------------------------------------------------
// head: whole D2RL dense head in one block; per-graph counts via binary
// search on sorted batch.
// ---------------------------------------------------------------------------
__global__ __launch_bounds__(256) void head_kernel(
    const float* __restrict__ gsum, const int* __restrict__ batch,
    const float* __restrict__ gn1, const float* __restrict__ bn1,
    const float* __restrict__ Wl1, const float* __restrict__ bl1,
    const float* __restrict__ gn2, const float* __restrict__ bn2,
    const float* __restrict__ Wl2, const float* __restrict__ bl2,
    const float* __restrict__ gn3, const float* __restrict__ bn3,
    const float* __restrict__ Wl3, const float* __restrict__ bl3,
    const float* __restrict__ Wout, const float* __restrict__ bout,
    float* __restrict__ out) {
  __shared__ float sxe[FH * NG];
  __shared__ float sz[FH * NG];
  __shared__ float sz2[FH * NG];
  __shared__ float sc1[FH], sh1[FH], sc2[2 * FH], sh2[2 * FH], sc3[2 * FH], sh3[2 * FH];

  int g = threadIdx.x;
  int lo = 0, hi = NN;
  while (lo < hi) { int mid = (lo + hi) >> 1; if (batch[mid] < g) lo = mid + 1; else hi = mid; }
  int lo2 = lo, hi2 = NN;
  while (lo2 < hi2) { int mid = (lo2 + hi2) >> 1; if (batch[mid] < g + 1) lo2 = mid + 1; else hi2 = mid; }
  float cnt = fmaxf((float)(lo2 - lo), 1.0f);

  float xe[FH];
#pragma unroll
  for (int c = 0; c < FH; c++) {
    xe[c] = gsum[g * FH + c] / cnt;
    sxe[c * NG + g] = xe[c];
  }
  __syncthreads();

  if (g < FH) {
    float s = 0.f, q = 0.f;
    for (int i = 0; i < NG; i++) {
      float v = sxe[g * NG + i];
      s += v; q += v * v;
    }
    float m = s * (1.0f / NG);
    float var = q * (1.0f / NG) - m * m;
    float sc = gn1[g] * rsqrtf(var + EPS);
    sc1[g] = sc;
    sh1[g] = bn1[g] - m * sc;
  }
  __syncthreads();

  float z1[FH];
  {
    float xb[FH];
#pragma unroll
    for (int k = 0; k < FH; k++) xb[k] = xe[k] * sc1[k] + sh1[k];
#pragma unroll
    for (int j = 0; j < FH; j++) {
      float acc = bl1[j];
#pragma unroll
      for (int k = 0; k < FH; k++) acc += Wl1[j * FH + k] * xb[k];
      z1[j] = fmaxf(acc, 0.f);
      sz[j * NG + g] = z1[j];
    }
  }
  __syncthreads();

  if (g < 2 * FH) {
    const float* col = (g < FH) ? (sz + g * NG) : (sxe + (g - FH) * NG);
    float s = 0.f, q = 0.f;
    for (int i = 0; i < NG; i++) {
      float v = col[i];
      s += v; q += v * v;
    }
    float m = s * (1.0f / NG);
    float var = q * (1.0f / NG) - m * m;
    float sc = gn2[g] * rsqrtf(var + EPS);
    sc2[g] = sc;
    sh2[g] = bn2[g] - m * sc;
  }
  __syncthreads();

  float z2[FH];
  {
    float cat[2 * FH];
#pragma unroll
    for (int k = 0; k < FH; k++) {
      cat[k] = z1[k] * sc2[k] + sh2[k];
      cat[FH + k] = xe[k] * sc2[FH + k] + sh2[FH + k];
    }
#pragma unroll
    for (int j = 0; j < FH; j++) {
      float acc = bl2[j];
#pragma unroll
      for (int k = 0; k < 2 * FH; k++) acc += Wl2[j * 2 * FH + k] * cat[k];
      z2[j] = fmaxf(acc, 0.f);
      sz2[j * NG + g] = z2[j];
    }
  }
  __syncthreads();

  if (g < 2 * FH) {
    const float* col = (g < FH) ? (sz2 + g * NG) : (sxe + (g - FH) * NG);
    float s = 0.f, q = 0.f;
    for (int i = 0; i < NG; i++) {
      float v = col[i];
      s += v; q += v * v;
    }
    float m = s * (1.0f / NG);
    float var = q * (1.0f / NG) - m * m;
    float sc = gn3[g] * rsqrtf(var + EPS);
    sc3[g] = sc;
    sh3[g] = bn3[g] - m * sc;
  }
  __syncthreads();

  {
    float cat[2 * FH];
#pragma unroll
    for (int k = 0; k < FH; k++) {
      cat[k] = z2[k] * sc3[k] + sh3[k];
      cat[FH + k] = xe[k] * sc3[FH + k] + sh3[FH + k];
    }
    float o = bout[0];
#pragma unroll
    for (int j = 0; j < FH; j++) {
      float acc = bl3[j];
#pragma unroll
      for (int k = 0; k < 2 * FH; k++) acc += Wl3[j * 2 * FH + k] * cat[k];
      o += Wout[j] * fmaxf(acc, 0.f);
    }
    out[g] = o;
  }
}

// ---------------------------------------------------------------------------
extern "C" void kernel_launch(void* const* d_in, const int* in_sizes, int n_in,
                              void* d_out, int out_size, void* d_ws, size_t ws_size,
                              hipStream_t stream) {
  const float* x    = (const float*)d_in[0];
  const int*   ei   = (const int*)d_in[1];
  const int*   batch= (const int*)d_in[2];
  const float* W1l  = (const float*)d_in[3];
  const float* W1r  = (const float*)d_in[4];
  const float* b1   = (const float*)d_in[5];
  const float* g1   = (const float*)d_in[6];
  const float* be1  = (const float*)d_in[7];
  const float* W2l  = (const float*)d_in[8];
  const float* W2r  = (const float*)d_in[9];
  const float* b2   = (const float*)d_in[10];
  const float* gn1  = (const float*)d_in[11];
  const float* bn1  = (const float*)d_in[12];
  const float* Wl1  = (const float*)d_in[13];
  const float* bl1  = (const float*)d_in[14];
  const float* gn2  = (const float*)d_in[15];
  const float* bn2  = (const float*)d_in[16];
  const float* Wl2  = (const float*)d_in[17];
  const float* bl2  = (const float*)d_in[18];
  const float* gn3  = (const float*)d_in[19];
  const float* bn3  = (const float*)d_in[20];
  const float* Wl3  = (const float*)d_in[21];
  const float* bl3  = (const float*)d_in[22];
  const float* Wout = (const float*)d_in[23];
  const float* bout = (const float*)d_in[24];

  const int sageBlocks = (NN * 4 + 255) / 256;  // 1563

  int* wi = (int*)d_ws;
  // zeroed region:
  int*   degi    = wi;                          // [NN]
  float* gsum    = (float*)(wi + NN);           // [NG*FH] = 4096
  // non-zeroed:
  int*   row_ptr = wi + NN + NG * FH;           // [NN+1]
  int*   cursor  = row_ptr + NN + 1;            // [NN]
  int*   csr_src = cursor + NN;                 // [NE]
  int*   bsum    = csr_src + NE;                // [NSB]
  int*   bpre    = bsum + NSB;                  // [NSB]
  float* partials= (float*)(bpre + NSB);        // [sageBlocks*32]
  float* scsh    = partials + sageBlocks * 32;  // [32]
  float* y1      = scsh + 32;                   // [NN*16] (reused as p2)
  float* r1      = y1 + NN * FH;                // [NN*16] (reused as r2)
  float* h1      = r1 + NN * FH;                // [NN*16]
  float* p2      = y1;
  float* r2      = r1;

  hipMemsetAsync(d_ws, 0, (size_t)(NN + NG * FH) * sizeof(int), stream);

  int nodeBlocks = (NN + 255) / 256;
  int edgeBlocks = (NE + 255) / 256;

  hist_kernel<<<edgeBlocks, 256, 0, stream>>>(ei, degi);
  scan_reduce_kernel<<<NSB, 256, 0, stream>>>(degi, bsum);
  scan_mid_kernel<<<1, 256, 0, stream>>>(bsum, bpre, row_ptr);
  scan_out_kernel<<<NSB, 256, 0, stream>>>(degi, bpre, row_ptr, cursor);
  scatter_kernel<<<edgeBlocks, 256, 0, stream>>>(ei, cursor, csr_src);
  proj1_kernel<<<nodeBlocks, 256, 0, stream>>>(x, W1l, W1r, y1, r1);
  sage1_kernel<<<sageBlocks, 256, 0, stream>>>(row_ptr, csr_src, y1, r1, b1, h1, partials);
  bn1_params_kernel<<<1, 1024, 0, stream>>>(partials, sageBlocks, g1, be1, scsh);
  proj2_kernel<<<nodeBlocks, 256, 0, stream>>>(h1, scsh, W2l, W2r, p2, r2);
  sage2_kernel<<<sageBlocks, 256, 0, stream>>>(row_ptr, csr_src, p2, r2, b2, batch, gsum);
  head_kernel<<<1, 256, 0, stream>>>(gsum, batch, gn1, bn1, Wl1, bl1,
                                     gn2, bn2, Wl2, bl2, gn3, bn3, Wl3, bl3,
                                     Wout, bout, (float*)d_out);
}